// Round 3
// baseline (1620.499 us; speedup 1.0000x reference)
//
#include <hip/hip_runtime.h>

typedef unsigned short u16;
typedef unsigned int u32;

using short8 = __attribute__((ext_vector_type(8))) short;
using f32x4  = __attribute__((ext_vector_type(4))) float;

constexpr int kB = 2, kT = 2048, kD = 2048, kH = 16, kK = 128, kV = 128;
constexpr int kM  = kB * kT;   // 4096 tokens
constexpr int kHK = kH * kK;   // 2048
constexpr int kHV = kH * kV;   // 2048

// ---------------- workspace layout (bytes). Overlays are deliberate. -------
constexpr size_t OFF_XB    = 0;          // bf16 x            16777216
constexpr size_t OFF_WQB   = 16777216;   // bf16 Wq            8388608
constexpr size_t OFF_WKB   = 25165824;   // bf16 Wk            8388608
constexpr size_t OFF_QC    = 0;          // f32 qc [B,H,T,K]  33554432 (aliases xb+Wqb+Wkb, dead by then)
constexpr size_t OFF_WVB   = 33554432;   // bf16 Wv            8388608
constexpr size_t OFF_WF1B  = 41943040;   // bf16 Wf1            524288
constexpr size_t OFF_WG1B  = 42467328;   // bf16 Wg1            524288
constexpr size_t OFF_WF2B  = 42991616;   // bf16 Wf2            524288
constexpr size_t OFF_WG2B  = 43515904;   // bf16 Wg2            524288
constexpr size_t OFF_WBP   = 44040192;   // bf16 Wb padded to [128,2048] 524288
constexpr size_t OFF_F1B   = 44564480;   // bf16 f1 [4096,128] 1048576
constexpr size_t OFF_G1B   = 45613056;   // bf16 g1 [4096,128] 1048576
constexpr size_t OFF_BRAW  = 46661632;   // f32 braw [4096,128] 2097152
constexpr size_t OFF_QRAW  = 48758784;   // bf16 qraw          16777216
constexpr size_t OFF_KRAW  = 65536000;   // bf16 kraw          16777216
constexpr size_t OFF_YF    = 48758784;   // f32 y [B,H,T,V]    33554432 (aliases qraw+kraw, dead by then)
constexpr size_t OFF_VRAW  = 82313216;   // bf16 vraw          16777216
constexpr size_t OFF_YGB   = 82313216;   // bf16 yg            16777216 (aliases vraw, dead by then)
constexpr size_t OFF_GRAW  = 99090432;   // bf16 g_raw         16777216
constexpr size_t OFF_GATEB = 115867648;  // bf16 gate          16777216
constexpr size_t OFF_WOUTB = 132644864;  // bf16 Wout           8388608
constexpr size_t OFF_KC    = 141033472;  // f32 kc             33554432
constexpr size_t OFF_VC    = 174587904;  // f32 vc             33554432
constexpr size_t OFF_DEC   = 208142336;  // f32 decay          33554432
constexpr size_t OFF_BETA  = 241696768;  // f32 beta [B,H,T]     262144
// total need: 241958912 bytes (~231 MB)

// ---------------- small helpers ----------------
__device__ __forceinline__ u16 f2bf(float f) {
  union { float f; u32 u; } a; a.f = f;
  u32 u = a.u;
  u += 0x7fffu + ((u >> 16) & 1u);   // round-to-nearest-even
  return (u16)(u >> 16);
}
__device__ __forceinline__ float bflo(u32 u) {
  union { u32 u; float f; } a; a.u = u << 16; return a.f;
}
__device__ __forceinline__ float bfhi(u32 u) {
  union { u32 u; float f; } a; a.u = u & 0xffff0000u; return a.f;
}
__device__ __forceinline__ float sigmoidf(float x) { return 1.0f / (1.0f + expf(-x)); }

#define GL_AS1 __attribute__((address_space(1)))
#define GL_AS3 __attribute__((address_space(3)))
// async global->LDS, 16B per lane. LDS dest must be wave-uniform-base + lane*16.
__device__ __forceinline__ void async_lds16(const void* g, void* l) {
  __builtin_amdgcn_global_load_lds((GL_AS1 u32*)(size_t)g,
                                   (GL_AS3 u32*)(u32)(size_t)l, 16, 0, 0);
}

// ---------------- cast / pad kernels ----------------
__global__ __launch_bounds__(256) void cast_bf16(const float* __restrict__ in,
                                                 u16* __restrict__ out, int n) {
  int i = (blockIdx.x * 256 + threadIdx.x) * 4;
  if (i >= n) return;
  float4 v = *(const float4*)(in + i);
  uint2 st;
  st.x = (u32)f2bf(v.x) | ((u32)f2bf(v.y) << 16);
  st.y = (u32)f2bf(v.z) | ((u32)f2bf(v.w) << 16);
  *(uint2*)(out + i) = st;
}

// Wb [16,2048] f32 -> [128,2048] bf16 zero-padded
__global__ __launch_bounds__(256) void pad_wb(const float* __restrict__ Wb,
                                              u16* __restrict__ out) {
  int i = (blockIdx.x * 256 + threadIdx.x) * 4;  // < 262144
  int row = i >> 11;
  uint2 st; st.x = 0; st.y = 0;
  if (row < 16) {
    float4 v = *(const float4*)(Wb + i);
    st.x = (u32)f2bf(v.x) | ((u32)f2bf(v.y) << 16);
    st.y = (u32)f2bf(v.z) | ((u32)f2bf(v.w) << 16);
  }
  *(uint2*)(out + i) = st;
}

// ---------------- bf16 MFMA GEMM:  C[m,n] = sum_k A[m,k] * B[n,k] ----------
// A: [M,K] bf16 row-major, B: [N,K] bf16 row-major. M%128==0, N%128==0, K%32==0.
template <bool BF16OUT>
__global__ __launch_bounds__(256) void gemm_bt(const u16* __restrict__ A,
                                               const u16* __restrict__ B,
                                               void* __restrict__ Cout,
                                               int M, int N, int K) {
  __shared__ u16 As[128 * 32];
  __shared__ u16 Bs[128 * 32];
  const int tid  = threadIdx.x;
  const int lane = tid & 63;
  const int wave = tid >> 6;
  const int wm = (wave >> 1) * 64;
  const int wn = (wave & 1) * 64;
  const long row0 = (long)blockIdx.x * 128;
  const long col0 = (long)blockIdx.y * 128;
  const int srow = tid >> 2;
  const int scol = (tid & 3) * 8;
  const u16* aptr = A + (row0 + srow) * (size_t)K + scol;
  const u16* bptr = B + (col0 + srow) * (size_t)K + scol;
  u16* asd  = &As[tid * 8];
  u16* asd2 = &As[2048 + tid * 8];
  u16* bsd  = &Bs[tid * 8];
  u16* bsd2 = &Bs[2048 + tid * 8];
  const int mrow = lane & 15;
  const int kq = (lane >> 4) * 8;
  f32x4 acc[4][4] = {};
  for (int k0 = 0; k0 < K; k0 += 32) {
    async_lds16(aptr, asd);
    async_lds16(aptr + (size_t)64 * K, asd2);
    async_lds16(bptr, bsd);
    async_lds16(bptr + (size_t)64 * K, bsd2);
    aptr += 32; bptr += 32;
    __syncthreads();   // drains vmcnt -> staged data visible
    short8 af[4], bfr[4];
#pragma unroll
    for (int i = 0; i < 4; ++i)
      af[i] = *(const short8*)(&As[(wm + i * 16 + mrow) * 32 + kq]);
#pragma unroll
    for (int j = 0; j < 4; ++j)
      bfr[j] = *(const short8*)(&Bs[(wn + j * 16 + mrow) * 32 + kq]);
#pragma unroll
    for (int i = 0; i < 4; ++i)
#pragma unroll
      for (int j = 0; j < 4; ++j)
        acc[i][j] = __builtin_amdgcn_mfma_f32_16x16x32_bf16(af[i], bfr[j], acc[i][j], 0, 0, 0);
    __syncthreads();   // all ds_reads done before next staging overwrites
  }
  const int cn = lane & 15;
  const int rq = (lane >> 4) * 4;
#pragma unroll
  for (int i = 0; i < 4; ++i)
#pragma unroll
    for (int j = 0; j < 4; ++j) {
      size_t r = (size_t)(row0 + wm + i * 16 + rq);
      size_t c = (size_t)(col0 + wn + j * 16 + cn);
#pragma unroll
      for (int rr = 0; rr < 4; ++rr) {
        if constexpr (BF16OUT)
          ((u16*)Cout)[(r + rr) * N + c] = f2bf(acc[i][j][rr]);
        else
          ((float*)Cout)[(r + rr) * N + c] = acc[i][j][rr];
      }
    }
}

// ---------------- conv(4-tap causal) + silu + l2norm + decay + beta --------
// one wave per (b,t,h); lane handles channels 2*lane, 2*lane+1
__global__ __launch_bounds__(256) void convprep(
    const u16* __restrict__ qraw, const u16* __restrict__ kraw,
    const u16* __restrict__ vraw, const u16* __restrict__ graw,
    const float* __restrict__ braw,
    const float* __restrict__ qcw, const float* __restrict__ kcw,
    const float* __restrict__ vcw, const float* __restrict__ A_log,
    const float* __restrict__ dt_bias,
    float* __restrict__ qc, float* __restrict__ kc, float* __restrict__ vc,
    float* __restrict__ dec, float* __restrict__ beta) {
  const int wid  = blockIdx.x * 4 + (threadIdx.x >> 6);
  const int lane = threadIdx.x & 63;
  const int h  = wid & 15;
  const int bt = wid >> 4;        // b*T + t
  const int t  = bt & (kT - 1);
  const int b  = bt >> 11;
  const int c0 = lane * 2;
  const size_t colofs = (size_t)h * kK + c0;
  const size_t rowb = (size_t)bt * kHK + colofs;
  const float* wq = qcw + colofs * 4;
  const float* wk = kcw + colofs * 4;
  const float* wv = vcw + colofs * 4;
  float qa0 = 0, qa1 = 0, ka0 = 0, ka1 = 0, va0 = 0, va1 = 0;
#pragma unroll
  for (int i = 0; i < 4; ++i) {       // tap i multiplies x[t-3+i]
    int tt = t - 3 + i;
    if (tt >= 0) {
      size_t ro = rowb - (size_t)(3 - i) * kHK;
      u32 uq = *(const u32*)(qraw + ro);
      u32 uk = *(const u32*)(kraw + ro);
      u32 uv = *(const u32*)(vraw + ro);
      qa0 += bflo(uq) * wq[i];  qa1 += bfhi(uq) * wq[4 + i];
      ka0 += bflo(uk) * wk[i];  ka1 += bfhi(uk) * wk[4 + i];
      va0 += bflo(uv) * wv[i];  va1 += bfhi(uv) * wv[4 + i];
    }
  }
  qa0 *= sigmoidf(qa0); qa1 *= sigmoidf(qa1);
  ka0 *= sigmoidf(ka0); ka1 *= sigmoidf(ka1);
  va0 *= sigmoidf(va0); va1 *= sigmoidf(va1);
  float sq = qa0 * qa0 + qa1 * qa1;
  float sk = ka0 * ka0 + ka1 * ka1;
#pragma unroll
  for (int m = 1; m < 64; m <<= 1) {
    sq += __shfl_xor(sq, m);
    sk += __shfl_xor(sk, m);
  }
  float qinv = 1.0f / fmaxf(sqrtf(sq), 1e-12f);
  float kinv = 1.0f / fmaxf(sqrtf(sk), 1e-12f);
  const size_t outb = ((size_t)(b * kH + h) * kT + t) * kK + c0;
  *(float2*)(qc + outb) = make_float2(qa0 * qinv, qa1 * qinv);
  *(float2*)(kc + outb) = make_float2(ka0 * kinv, ka1 * kinv);
  *(float2*)(vc + outb) = make_float2(va0, va1);
  // decay = exp(-exp(A_log)*softplus(g_raw + dt_bias))
  u32 ug = *(const u32*)(graw + rowb);
  float Ae = expf(A_log[h]);
  float g0 = bflo(ug) + dt_bias[colofs];
  float g1 = bfhi(ug) + dt_bias[colofs + 1];
  float sp0 = (g0 > 15.f) ? g0 : log1pf(expf(g0));
  float sp1 = (g1 > 15.f) ? g1 : log1pf(expf(g1));
  *(float2*)(dec + outb) = make_float2(expf(-Ae * sp0), expf(-Ae * sp1));
  if (lane == 0) {
    float bv = braw[(size_t)bt * 128 + h];
    beta[(size_t)(b * kH + h) * kT + t] = sigmoidf(bv);
  }
}

// ---------------- KDA delta-rule scan v3 ----------------
// 512 blocks x 4 waves = 2048 waves = 2 waves/SIMD (2 blocks/CU).
// Wave covers 2 v-cols: lane = vcl*32 + kg, kg in [0,32) holds 4 k-rows
// (float4 state). Dot/output reductions: 5 shfl_xor rounds (1,2,4,8,16).
// Register prefetch of step t+1 operands; o-reduction deferred one step.
// XCD swizzle: the 16 blocks sharing a bh have equal blockIdx%8.
constexpr int kC = 16;   // chunk length (timesteps per stage)

__global__ __launch_bounds__(256) void kda_scan(
    const float* __restrict__ qc, const float* __restrict__ kc,
    const float* __restrict__ vcp, const float* __restrict__ dec,
    const float* __restrict__ betap, float* __restrict__ yf) {
  __shared__ float qsh[2][kC][kK];
  __shared__ float ksh[2][kC][kK];
  __shared__ float dsh[2][kC][kK];
  __shared__ float vsh[2][kC][8];
  __shared__ float bsh[2][kC];
  const int tid  = threadIdx.x;
  const int lane = tid & 63;
  const int w    = tid >> 6;
  const int bid  = blockIdx.x;
  const int x    = bid & 7;            // XCD slot (heuristic)
  const int g    = bid >> 3;           // [0,64)
  const int bh   = (g & 3) * 8 + x;    // [0,32)
  const int cb   = (g >> 2) * 8;       // block's first v-col (8 wide)
  const int kg   = lane & 31;          // 4 k-rows: [kg*4, kg*4+4)
  const int vcl  = lane >> 5;          // which of the wave's 2 v-cols
  const int vi   = cb + w * 2 + vcl;   // this lane's v-column
  const float* qb = qc  + (size_t)bh * kT * kK;
  const float* kb = kc  + (size_t)bh * kT * kK;
  const float* db = dec + (size_t)bh * kT * kK;
  const float* vb = vcp + (size_t)bh * kT * kV;
  const float* bp = betap + (size_t)bh * kT;
  float* yb = yf + (size_t)bh * kT * kV;

  auto stage = [&](int buf, int t0) {
    const size_t go = (size_t)t0 * kK;   // float offset of chunk start
#pragma unroll
    for (int i = 0; i < 2; ++i) {
      int ofs = (i * 256 + tid) * 4;     // float index within 8KB chunk
      async_lds16(qb + go + ofs, &qsh[buf][0][0] + ofs);
      async_lds16(kb + go + ofs, &ksh[buf][0][0] + ofs);
      async_lds16(db + go + ofs, &dsh[buf][0][0] + ofs);
    }
    if (tid < 128) {
      int t = tid >> 3, c = tid & 7;
      vsh[buf][t][c] = vb[(size_t)(t0 + t) * kV + cb + c];
    }
    if (tid < kC) bsh[buf][tid] = bp[t0 + tid];
  };

  stage(0, 0);
  float S0 = 0, S1 = 0, S2 = 0, S3 = 0;
  float oprev = 0.f;
  int tprev = -1;
  for (int ch = 0; ch < kT / kC; ++ch) {
    const int cur = ch & 1;
    __syncthreads();                       // staged chunk `cur` is ready
    if (ch + 1 < kT / kC) stage(cur ^ 1, (ch + 1) * kC);
    // step-0 operands
    float4 kk = *(const float4*)&ksh[cur][0][kg * 4];
    float4 dd = *(const float4*)&dsh[cur][0][kg * 4];
    float4 qq = *(const float4*)&qsh[cur][0][kg * 4];
    float vt = vsh[cur][0][w * 2 + vcl];
    float bt = bsh[cur][0];
#pragma unroll
    for (int tt = 0; tt < kC; ++tt) {
      // prefetch step tt+1 operands (tt=15: dummy re-read of step 15)
      const int tn = (tt < kC - 1) ? tt + 1 : tt;
      float4 kn = *(const float4*)&ksh[cur][tn][kg * 4];
      float4 dn = *(const float4*)&dsh[cur][tn][kg * 4];
      float4 qn = *(const float4*)&qsh[cur][tn][kg * 4];
      float vn = vsh[cur][tn][w * 2 + vcl];
      float bn = bsh[cur][tn];
      // finish previous step's output reduction (off the S critical path)
      {
        float o = oprev;
        o += __shfl_xor(o, 1);
        o += __shfl_xor(o, 2);
        o += __shfl_xor(o, 4);
        o += __shfl_xor(o, 8);
        o += __shfl_xor(o, 16);
        if (tprev >= 0 && kg == 0) yb[(size_t)tprev * kV + vi] = o;
      }
      // S' = decay*S ; err = v - k.S' ; S = S' + beta*err*k
      float t0 = dd.x * S0, t1 = dd.y * S1, t2 = dd.z * S2, t3 = dd.w * S3;
      float dot = (kk.x * t0 + kk.y * t1) + (kk.z * t2 + kk.w * t3);
      dot += __shfl_xor(dot, 1);
      dot += __shfl_xor(dot, 2);
      dot += __shfl_xor(dot, 4);
      dot += __shfl_xor(dot, 8);
      dot += __shfl_xor(dot, 16);
      float u = bt * (vt - dot);
      S0 = fmaf(u, kk.x, t0); S1 = fmaf(u, kk.y, t1);
      S2 = fmaf(u, kk.z, t2); S3 = fmaf(u, kk.w, t3);
      // partial output (reduced next iteration)
      oprev = (qq.x * S0 + qq.y * S1) + (qq.z * S2 + qq.w * S3);
      tprev = ch * kC + tt;
      kk = kn; dd = dn; qq = qn; vt = vn; bt = bn;
    }
  }
  // final step's output
  {
    float o = oprev;
    o += __shfl_xor(o, 1);
    o += __shfl_xor(o, 2);
    o += __shfl_xor(o, 4);
    o += __shfl_xor(o, 8);
    o += __shfl_xor(o, 16);
    if (kg == 0) yb[(size_t)tprev * kV + vi] = o;
  }
}

// ---------------- rmsnorm * o_norm_w * sigmoid(gate+bg) -> bf16 -----------
__global__ __launch_bounds__(256) void postk(
    const float* __restrict__ yf, const u16* __restrict__ gateb,
    const float* __restrict__ bg, const float* __restrict__ onw,
    u16* __restrict__ ygb) {
  const int wid  = blockIdx.x * 4 + (threadIdx.x >> 6);
  const int lane = threadIdx.x & 63;
  const int h  = wid & 15;
  const int bt = wid >> 4;
  const int t  = bt & (kT - 1);
  const int b  = bt >> 11;
  const int v0 = lane * 2;
  const size_t yi = ((size_t)(b * kH + h) * kT + t) * kV + v0;
  float2 yv = *(const float2*)(yf + yi);
  float s = yv.x * yv.x + yv.y * yv.y;
#pragma unroll
  for (int m = 1; m < 64; m <<= 1) s += __shfl_xor(s, m);
  float scale = rsqrtf(s * (1.0f / 128.0f) + 1.1920929e-07f);
  const size_t gi = (size_t)bt * kHV + (size_t)h * kV + v0;
  u32 ug = *(const u32*)(gateb + gi);
  float g0 = bflo(ug) + bg[h * kV + v0];
  float g1 = bfhi(ug) + bg[h * kV + v0 + 1];
  float r0 = yv.x * scale * onw[v0] * sigmoidf(g0);
  float r1 = yv.y * scale * onw[v0 + 1] * sigmoidf(g1);
  *(u32*)(ygb + gi) = (u32)f2bf(r0) | ((u32)f2bf(r1) << 16);
}

// ---------------- host launcher ----------------
extern "C" void kernel_launch(void* const* d_in, const int* in_sizes, int n_in,
                              void* d_out, int out_size, void* d_ws, size_t ws_size,
                              hipStream_t stream) {
  (void)in_sizes; (void)n_in; (void)out_size; (void)ws_size;
  const float* x    = (const float*)d_in[0];
  const float* Wq   = (const float*)d_in[1];
  const float* Wk   = (const float*)d_in[2];
  const float* Wv   = (const float*)d_in[3];
  const float* Wf1  = (const float*)d_in[4];
  const float* Wf2  = (const float*)d_in[5];
  const float* Wb   = (const float*)d_in[6];
  const float* Wg1  = (const float*)d_in[7];
  const float* Wg2  = (const float*)d_in[8];
  const float* bg   = (const float*)d_in[9];
  const float* onw  = (const float*)d_in[10];
  const float* Wout = (const float*)d_in[11];
  const float* A_log   = (const float*)d_in[12];
  const float* dt_bias = (const float*)d_in[13];
  const float* qcw  = (const float*)d_in[14];
  const float* kcw  = (const float*)d_in[15];
  const float* vcw  = (const float*)d_in[16];

  char* ws = (char*)d_ws;
  u16* xb    = (u16*)(ws + OFF_XB);
  u16* Wqb   = (u16*)(ws + OFF_WQB);
  u16* Wkb   = (u16*)(ws + OFF_WKB);
  u16* Wvb   = (u16*)(ws + OFF_WVB);
  u16* Wf1b  = (u16*)(ws + OFF_WF1B);
  u16* Wg1b  = (u16*)(ws + OFF_WG1B);
  u16* Wf2b  = (u16*)(ws + OFF_WF2B);
  u16* Wg2b  = (u16*)(ws + OFF_WG2B);
  u16* Wbp   = (u16*)(ws + OFF_WBP);
  u16* Woutb = (u16*)(ws + OFF_WOUTB);
  u16* qraw  = (u16*)(ws + OFF_QRAW);
  u16* kraw  = (u16*)(ws + OFF_KRAW);
  u16* vraw  = (u16*)(ws + OFF_VRAW);
  u16* graw  = (u16*)(ws + OFF_GRAW);
  u16* gateb = (u16*)(ws + OFF_GATEB);
  u16* f1b   = (u16*)(ws + OFF_F1B);
  u16* g1b   = (u16*)(ws + OFF_G1B);
  u16* ygb   = (u16*)(ws + OFF_YGB);
  float* brawf = (float*)(ws + OFF_BRAW);
  float* qcf   = (float*)(ws + OFF_QC);
  float* kcf   = (float*)(ws + OFF_KC);
  float* vcf   = (float*)(ws + OFF_VC);
  float* decf  = (float*)(ws + OFF_DEC);
  float* betaf = (float*)(ws + OFF_BETA);
  float* yff   = (float*)(ws + OFF_YF);

  auto cast = [&](const float* src, u16* dst, int n) {
    cast_bf16<<<(n / 4 + 255) / 256, 256, 0, stream>>>(src, dst, n);
  };
  cast(x, xb, kM * kD);
  cast(Wq, Wqb, kHK * kD);
  cast(Wk, Wkb, kHK * kD);
  cast(Wv, Wvb, kHV * kD);
  cast(Wout, Woutb, kD * kHV);
  cast(Wf1, Wf1b, kV * kD);
  cast(Wg1, Wg1b, kV * kD);
  cast(Wf2, Wf2b, kHK * kV);
  cast(Wg2, Wg2b, kHV * kV);
  pad_wb<<<(128 * 2048 / 4 + 255) / 256, 256, 0, stream>>>(Wb, Wbp);

  dim3 blk(256);
  gemm_bt<true><<<dim3(kM / 128, kHK / 128), blk, 0, stream>>>(xb, Wqb, qraw, kM, kHK, kD);
  gemm_bt<true><<<dim3(kM / 128, kHK / 128), blk, 0, stream>>>(xb, Wkb, kraw, kM, kHK, kD);
  gemm_bt<true><<<dim3(kM / 128, kHV / 128), blk, 0, stream>>>(xb, Wvb, vraw, kM, kHV, kD);
  gemm_bt<true><<<dim3(kM / 128, 1), blk, 0, stream>>>(xb, Wf1b, f1b, kM, 128, kD);
  gemm_bt<true><<<dim3(kM / 128, 1), blk, 0, stream>>>(xb, Wg1b, g1b, kM, 128, kD);
  gemm_bt<false><<<dim3(kM / 128, 1), blk, 0, stream>>>(xb, Wbp, brawf, kM, 128, kD);
  gemm_bt<true><<<dim3(kM / 128, kHK / 128), blk, 0, stream>>>(f1b, Wf2b, graw, kM, kHK, kV);
  gemm_bt<true><<<dim3(kM / 128, kHV / 128), blk, 0, stream>>>(g1b, Wg2b, gateb, kM, kHV, kV);

  convprep<<<kB * kT * kH / 4, 256, 0, stream>>>(qraw, kraw, vraw, graw, brawf,
                                                 qcw, kcw, vcw, A_log, dt_bias,
                                                 qcf, kcf, vcf, decf, betaf);

  kda_scan<<<512, 256, 0, stream>>>(qcf, kcf, vcf, decf, betaf, yff);

  postk<<<kB * kT * kH / 4, 256, 0, stream>>>(yff, gateb, bg, onw, ygb);

  gemm_bt<false><<<dim3(kM / 128, kD / 128), blk, 0, stream>>>(ygb, Woutb, (float*)d_out, kM, kD, kHV);
}

// Round 4
// 1151.996 us; speedup vs baseline: 1.4067x; 1.4067x over previous
//
#include <hip/hip_runtime.h>

typedef unsigned short u16;
typedef unsigned int u32;

using short8 = __attribute__((ext_vector_type(8))) short;
using f32x4  = __attribute__((ext_vector_type(4))) float;

constexpr int kB = 2, kT = 2048, kD = 2048, kH = 16, kK = 128, kV = 128;
constexpr int kM  = kB * kT;   // 4096 tokens
constexpr int kHK = kH * kK;   // 2048
constexpr int kHV = kH * kV;   // 2048
constexpr int CC  = 16;        // scan chunk length
constexpr int NCH = kT / CC;   // 128 chunks
constexpr int VB  = 16;        // v-cols per p2 block (8 v-splits)

// ---------------- workspace layout (bytes). Overlays are deliberate. -------
constexpr size_t OFF_XB    = 0;          // bf16 x            16777216
constexpr size_t OFF_WQB   = 16777216;   // bf16 Wq            8388608
constexpr size_t OFF_WKB   = 25165824;   // bf16 Wk            8388608
constexpr size_t OFF_QC    = 0;          // f32 qc [bh][t][K] 33554432 (aliases xb+Wqb+Wkb, dead by then)
constexpr size_t OFF_WVB   = 33554432;   // bf16 Wv            8388608
constexpr size_t OFF_WF1B  = 41943040;   // bf16 Wf1            524288
constexpr size_t OFF_WG1B  = 42467328;   // bf16 Wg1            524288
constexpr size_t OFF_WF2B  = 42991616;   // bf16 Wf2            524288
constexpr size_t OFF_WG2B  = 43515904;   // bf16 Wg2            524288
constexpr size_t OFF_WBP   = 44040192;   // bf16 Wb padded to [128,2048] 524288
constexpr size_t OFF_F1B   = 44564480;   // bf16 f1 [4096,128] 1048576
constexpr size_t OFF_G1B   = 45613056;   // bf16 g1 [4096,128] 1048576
constexpr size_t OFF_BRAW  = 46661632;   // f32 braw [4096,128] 2097152
constexpr size_t OFF_QRAW  = 48758784;   // bf16 qraw          16777216
constexpr size_t OFF_KRAW  = 65536000;   // bf16 kraw          16777216
constexpr size_t OFF_YF    = 48758784;   // f32 y [bh][t][V]   33554432 (aliases qraw+kraw, dead by then)
constexpr size_t OFF_VRAW  = 82313216;   // bf16 vraw          16777216
constexpr size_t OFF_YGB   = 82313216;   // bf16 yg            16777216 (aliases vraw, dead by then)
constexpr size_t OFF_GRAW  = 99090432;   // bf16 g_raw         16777216
constexpr size_t OFF_LAM   = 99090432;   // f32 lamC [bh][ch][128]  2097152 (aliases graw, dead after convprep)
constexpr size_t OFF_WINV  = 101187584;  // f32 winv [bh][ch][16][16] 4194304
constexpr size_t OFF_MM    = 105381888;  // f32 M    [bh][ch][16][16] 4194304
constexpr size_t OFF_GATEB = 115867648;  // bf16 gate          16777216
constexpr size_t OFF_WOUTB = 132644864;  // bf16 Wout           8388608
constexpr size_t OFF_KC    = 141033472;  // f32 kc             33554432
constexpr size_t OFF_VC    = 174587904;  // f32 v transposed [bh*8+vs][t][16] 33554432
constexpr size_t OFF_DEC   = 208142336;  // f32 g (log-decay) -> kbar (p1 in-place) 33554432
constexpr size_t OFF_BETA  = 241696768;  // f32 beta [bh][t]     262144
// total need: 241958912 bytes (~231 MB)

// ---------------- small helpers ----------------
__device__ __forceinline__ u16 f2bf(float f) {
  union { float f; u32 u; } a; a.f = f;
  u32 u = a.u;
  u += 0x7fffu + ((u >> 16) & 1u);   // round-to-nearest-even
  return (u16)(u >> 16);
}
__device__ __forceinline__ float bflo(u32 u) {
  union { u32 u; float f; } a; a.u = u << 16; return a.f;
}
__device__ __forceinline__ float bfhi(u32 u) {
  union { u32 u; float f; } a; a.u = u & 0xffff0000u; return a.f;
}
__device__ __forceinline__ float sigmoidf(float x) { return 1.0f / (1.0f + expf(-x)); }

#define GL_AS1 __attribute__((address_space(1)))
#define GL_AS3 __attribute__((address_space(3)))
// async global->LDS, 16B per lane. LDS dest must be wave-uniform base + lane*16.
__device__ __forceinline__ void async_lds16(const void* g, void* l) {
  __builtin_amdgcn_global_load_lds((GL_AS1 u32*)(size_t)g,
                                   (GL_AS3 u32*)(u32)(size_t)l, 16, 0, 0);
}

// ---------------- cast / pad kernels ----------------
__global__ __launch_bounds__(256) void cast_bf16(const float* __restrict__ in,
                                                 u16* __restrict__ out, int n) {
  int i = (blockIdx.x * 256 + threadIdx.x) * 4;
  if (i >= n) return;
  float4 v = *(const float4*)(in + i);
  uint2 st;
  st.x = (u32)f2bf(v.x) | ((u32)f2bf(v.y) << 16);
  st.y = (u32)f2bf(v.z) | ((u32)f2bf(v.w) << 16);
  *(uint2*)(out + i) = st;
}

// Wb [16,2048] f32 -> [128,2048] bf16 zero-padded
__global__ __launch_bounds__(256) void pad_wb(const float* __restrict__ Wb,
                                              u16* __restrict__ out) {
  int i = (blockIdx.x * 256 + threadIdx.x) * 4;  // < 262144
  int row = i >> 11;
  uint2 st; st.x = 0; st.y = 0;
  if (row < 16) {
    float4 v = *(const float4*)(Wb + i);
    st.x = (u32)f2bf(v.x) | ((u32)f2bf(v.y) << 16);
    st.y = (u32)f2bf(v.z) | ((u32)f2bf(v.w) << 16);
  }
  *(uint2*)(out + i) = st;
}

// ---------------- bf16 MFMA GEMM:  C[m,n] = sum_k A[m,k] * B[n,k] ----------
template <bool BF16OUT>
__global__ __launch_bounds__(256) void gemm_bt(const u16* __restrict__ A,
                                               const u16* __restrict__ B,
                                               void* __restrict__ Cout,
                                               int M, int N, int K) {
  __shared__ u16 As[128 * 32];
  __shared__ u16 Bs[128 * 32];
  const int tid  = threadIdx.x;
  const int lane = tid & 63;
  const int wave = tid >> 6;
  const int wm = (wave >> 1) * 64;
  const int wn = (wave & 1) * 64;
  const long row0 = (long)blockIdx.x * 128;
  const long col0 = (long)blockIdx.y * 128;
  const int srow = tid >> 2;
  const int scol = (tid & 3) * 8;
  const u16* aptr = A + (row0 + srow) * (size_t)K + scol;
  const u16* bptr = B + (col0 + srow) * (size_t)K + scol;
  u16* asd  = &As[tid * 8];
  u16* asd2 = &As[2048 + tid * 8];
  u16* bsd  = &Bs[tid * 8];
  u16* bsd2 = &Bs[2048 + tid * 8];
  const int mrow = lane & 15;
  const int kq = (lane >> 4) * 8;
  f32x4 acc[4][4] = {};
  for (int k0 = 0; k0 < K; k0 += 32) {
    async_lds16(aptr, asd);
    async_lds16(aptr + (size_t)64 * K, asd2);
    async_lds16(bptr, bsd);
    async_lds16(bptr + (size_t)64 * K, bsd2);
    aptr += 32; bptr += 32;
    __syncthreads();
    short8 af[4], bfr[4];
#pragma unroll
    for (int i = 0; i < 4; ++i)
      af[i] = *(const short8*)(&As[(wm + i * 16 + mrow) * 32 + kq]);
#pragma unroll
    for (int j = 0; j < 4; ++j)
      bfr[j] = *(const short8*)(&Bs[(wn + j * 16 + mrow) * 32 + kq]);
#pragma unroll
    for (int i = 0; i < 4; ++i)
#pragma unroll
      for (int j = 0; j < 4; ++j)
        acc[i][j] = __builtin_amdgcn_mfma_f32_16x16x32_bf16(af[i], bfr[j], acc[i][j], 0, 0, 0);
    __syncthreads();
  }
  const int cn = lane & 15;
  const int rq = (lane >> 4) * 4;
#pragma unroll
  for (int i = 0; i < 4; ++i)
#pragma unroll
    for (int j = 0; j < 4; ++j) {
      size_t r = (size_t)(row0 + wm + i * 16 + rq);
      size_t c = (size_t)(col0 + wn + j * 16 + cn);
#pragma unroll
      for (int rr = 0; rr < 4; ++rr) {
        if constexpr (BF16OUT)
          ((u16*)Cout)[(r + rr) * N + c] = f2bf(acc[i][j][rr]);
        else
          ((float*)Cout)[(r + rr) * N + c] = acc[i][j][rr];
      }
    }
}

// ---------------- conv(4-tap causal) + silu + l2norm + g + beta ------------
// one wave per (b,t,h); lane handles channels 2*lane, 2*lane+1
__global__ __launch_bounds__(256) void convprep(
    const u16* __restrict__ qraw, const u16* __restrict__ kraw,
    const u16* __restrict__ vraw, const u16* __restrict__ graw,
    const float* __restrict__ braw,
    const float* __restrict__ qcw, const float* __restrict__ kcw,
    const float* __restrict__ vcw, const float* __restrict__ A_log,
    const float* __restrict__ dt_bias,
    float* __restrict__ qc, float* __restrict__ kc, float* __restrict__ vt,
    float* __restrict__ gdec, float* __restrict__ beta) {
  const int wid  = blockIdx.x * 4 + (threadIdx.x >> 6);
  const int lane = threadIdx.x & 63;
  const int h  = wid & 15;
  const int bt = wid >> 4;        // b*T + t
  const int t  = bt & (kT - 1);
  const int b  = bt >> 11;
  const int c0 = lane * 2;
  const size_t colofs = (size_t)h * kK + c0;
  const size_t rowb = (size_t)bt * kHK + colofs;
  const float* wq = qcw + colofs * 4;
  const float* wk = kcw + colofs * 4;
  const float* wv = vcw + colofs * 4;
  float qa0 = 0, qa1 = 0, ka0 = 0, ka1 = 0, va0 = 0, va1 = 0;
#pragma unroll
  for (int i = 0; i < 4; ++i) {       // tap i multiplies x[t-3+i]
    int tt = t - 3 + i;
    if (tt >= 0) {
      size_t ro = rowb - (size_t)(3 - i) * kHK;
      u32 uq = *(const u32*)(qraw + ro);
      u32 uk = *(const u32*)(kraw + ro);
      u32 uv = *(const u32*)(vraw + ro);
      qa0 += bflo(uq) * wq[i];  qa1 += bfhi(uq) * wq[4 + i];
      ka0 += bflo(uk) * wk[i];  ka1 += bfhi(uk) * wk[4 + i];
      va0 += bflo(uv) * wv[i];  va1 += bfhi(uv) * wv[4 + i];
    }
  }
  qa0 *= sigmoidf(qa0); qa1 *= sigmoidf(qa1);
  ka0 *= sigmoidf(ka0); ka1 *= sigmoidf(ka1);
  va0 *= sigmoidf(va0); va1 *= sigmoidf(va1);
  float sq = qa0 * qa0 + qa1 * qa1;
  float sk = ka0 * ka0 + ka1 * ka1;
#pragma unroll
  for (int m = 1; m < 64; m <<= 1) {
    sq += __shfl_xor(sq, m);
    sk += __shfl_xor(sk, m);
  }
  float qinv = 1.0f / fmaxf(sqrtf(sq), 1e-12f);
  float kinv = 1.0f / fmaxf(sqrtf(sk), 1e-12f);
  const int bh = b * kH + h;
  const size_t outb = ((size_t)bh * kT + t) * kK + c0;
  *(float2*)(qc + outb) = make_float2(qa0 * qinv, qa1 * qinv);
  *(float2*)(kc + outb) = make_float2(ka0 * kinv, ka1 * kinv);
  // v in transposed layout [bh*8 + vsplit][t][16]
  const size_t vtb = ((size_t)(bh * 8 + (c0 >> 4)) * kT + t) * VB + (c0 & 15);
  *(float2*)(vt + vtb) = make_float2(va0, va1);
  // g = -exp(A_log)*softplus(g_raw + dt_bias)  (log decay; p1 consumes)
  u32 ug = *(const u32*)(graw + rowb);
  float Ae = expf(A_log[h]);
  float g0 = bflo(ug) + dt_bias[colofs];
  float g1 = bfhi(ug) + dt_bias[colofs + 1];
  float sp0 = (g0 > 15.f) ? g0 : log1pf(expf(g0));
  float sp1 = (g1 > 15.f) ? g1 : log1pf(expf(g1));
  *(float2*)(gdec + outb) = make_float2(-Ae * sp0, -Ae * sp1);
  if (lane == 0) {
    float bv = braw[(size_t)bt * 128 + h];
    beta[(size_t)bh * kT + t] = sigmoidf(bv);
  }
}

// ---------------- KDA chunked scan, pass 1 (parallel over bh x chunk) -----
// In-place: qc->qhat=q*exp(G), kc->khat=k*exp(G), gdec->kbar=k*exp(G_C - G).
// Also lamC=exp(G_C), Winv=(I+B trilA)^{-1}B, M[t][s]=sum_k q_t k_s e^{G_t-G_s}.
__global__ __launch_bounds__(256) void kda_p1(
    float* __restrict__ qc, float* __restrict__ kc, float* __restrict__ gk,
    const float* __restrict__ betap, float* __restrict__ lamC,
    float* __restrict__ winv, float* __restrict__ mmat) {
  __shared__ float kL[CC][132], qL[CC][132], gL[CC][132];
  __shared__ float As[CC][CC], Ms[CC][CC];
  __shared__ float bet[CC];
  const int tid = threadIdx.x;
  const int bh = blockIdx.x >> 7;
  const int ch = blockIdx.x & 127;
  const size_t base = ((size_t)bh * kT + ch * CC) * kK;
  {
    int e = tid * 8;
    int t = e >> 7, k = e & 127;
    *(float4*)&kL[t][k]     = *(const float4*)(kc + base + e);
    *(float4*)&kL[t][k + 4] = *(const float4*)(kc + base + e + 4);
    *(float4*)&qL[t][k]     = *(const float4*)(qc + base + e);
    *(float4*)&qL[t][k + 4] = *(const float4*)(qc + base + e + 4);
    *(float4*)&gL[t][k]     = *(const float4*)(gk + base + e);
    *(float4*)&gL[t][k + 4] = *(const float4*)(gk + base + e + 4);
    if (tid < CC) bet[tid] = betap[(size_t)bh * kT + ch * CC + tid];
  }
  __syncthreads();
  if (tid < kK) {        // inclusive cumsum of g over t (per k) -> G
    float a = gL[0][tid];
#pragma unroll
    for (int t = 1; t < CC; ++t) { a += gL[t][tid]; gL[t][tid] = a; }
  }
  __syncthreads();
  {  // elementwise transforms (8 consecutive k in one row per thread)
    int e = tid * 8;
    int t = e >> 7, k = e & 127;
    float kh[8], qh[8], kb[8];
#pragma unroll
    for (int j = 0; j < 8; ++j) {
      float G  = gL[t][k + j];
      float eg = __expf(G);
      kh[j] = kL[t][k + j] * eg;
      qh[j] = qL[t][k + j] * eg;
      kb[j] = kL[t][k + j] * __expf(gL[CC - 1][k + j] - G);
    }
    *(float4*)(kc + base + e)     = make_float4(kh[0], kh[1], kh[2], kh[3]);
    *(float4*)(kc + base + e + 4) = make_float4(kh[4], kh[5], kh[6], kh[7]);
    *(float4*)(qc + base + e)     = make_float4(qh[0], qh[1], qh[2], qh[3]);
    *(float4*)(qc + base + e + 4) = make_float4(qh[4], qh[5], qh[6], qh[7]);
    *(float4*)(gk + base + e)     = make_float4(kb[0], kb[1], kb[2], kb[3]);
    *(float4*)(gk + base + e + 4) = make_float4(kb[4], kb[5], kb[6], kb[7]);
    if (tid < kK)
      lamC[((size_t)bh * NCH + ch) * kK + tid] = __expf(gL[CC - 1][tid]);
  }
  {  // A[t][s] (s<t), M[t][s] (s<=t): decay-weighted Gram, direct exp of diff
    const int t = tid >> 4, s = tid & 15;
    float av = 0.f, mv = 0.f;
    for (int k = 0; k < kK; ++k) {
      float w  = __expf(gL[t][k] - gL[s][k]);
      float ks = kL[s][k] * w;
      av = fmaf(kL[t][k], ks, av);
      mv = fmaf(qL[t][k], ks, mv);
    }
    As[t][s] = (s < t)  ? av : 0.f;
    Ms[t][s] = (s <= t) ? mv : 0.f;
  }
  __syncthreads();
  if (tid < CC) {  // forward-substitute X = (I + B trilA)^{-1} B, col s=tid
    const int s = tid;
    float x[CC];
#pragma unroll
    for (int t = 0; t < CC; ++t) {
      float sum = 0.f;
      for (int r = 0; r < t; ++r) sum += As[t][r] * x[r];
      x[t] = ((t == s) ? bet[t] : 0.f) - bet[t] * sum;
    }
    const size_t wb = ((size_t)bh * NCH + ch) * 256;
#pragma unroll
    for (int t = 0; t < CC; ++t) winv[wb + t * 16 + s] = x[t];
  }
  mmat[((size_t)bh * NCH + ch) * 256 + tid] = Ms[tid >> 4][tid & 15];
}

// ---------------- KDA chunked scan, pass 2 (sequential over 128 chunks) ---
// 256 blocks = 32 bh x 8 v-splits (16 v-cols). State S^T[vc][k] in LDS.
// Per chunk: T1 = V - Khat S0; U = Winv T1; O = Qhat S0 + M U; S = lam*S0 + Kbar^T U.
__global__ __launch_bounds__(256) void kda_p2(
    const float* __restrict__ khat, const float* __restrict__ qhat,
    const float* __restrict__ kbar, const float* __restrict__ lamC,
    const float* __restrict__ winv, const float* __restrict__ mmat,
    const float* __restrict__ vt, float* __restrict__ yf) {
  __shared__ float S0T[VB][kK + 4];
  __shared__ float khs[2][CC][kK];
  __shared__ float qhs[2][CC][kK];
  __shared__ float kbs[2][CC][kK];
  __shared__ float vs_[2][CC][VB];
  __shared__ float ws_[2][CC][CC];
  __shared__ float ms_[2][CC][CC];
  __shared__ float lam_[2][kK];
  __shared__ float T1s[CC][VB];
  __shared__ float QSs[CC][VB];
  __shared__ float Us[CC][VB];
  const int tid = threadIdx.x;
  const int blk = blockIdx.x;
  const int bh  = (blk & 7) + ((blk >> 6) << 3);  // same-bh blocks share XCD slot
  const int vs  = (blk >> 3) & 7;
  const int cb  = vs * VB;
  const int tA = tid >> 4, vA = tid & 15;   // phase A/B/O map
  const int vC = tid >> 4, kg = tid & 15;   // state-update map; k0 = kg*8

  auto stage = [&](int buf, int ch) {
    const size_t cbase = ((size_t)bh * kT + ch * CC) * kK;
    int o0 = tid * 4, o1 = (tid + 256) * 4;
    async_lds16(khat + cbase + o0, &khs[buf][0][0] + o0);
    async_lds16(khat + cbase + o1, &khs[buf][0][0] + o1);
    async_lds16(qhat + cbase + o0, &qhs[buf][0][0] + o0);
    async_lds16(qhat + cbase + o1, &qhs[buf][0][0] + o1);
    async_lds16(kbar + cbase + o0, &kbs[buf][0][0] + o0);
    async_lds16(kbar + cbase + o1, &kbs[buf][0][0] + o1);
    const int wv = tid >> 6, ln = (tid & 63) * 4;
    const size_t sm = (size_t)bh * NCH + ch;
    if (wv == 0) {
      async_lds16(winv + (sm << 8) + ln, &ws_[buf][0][0] + ln);
    } else if (wv == 1) {
      async_lds16(mmat + (sm << 8) + ln, &ms_[buf][0][0] + ln);
    } else if (wv == 2) {
      if (ln < 128) async_lds16(lamC + (sm << 7) + ln, &lam_[buf][0] + ln);
    } else {
      async_lds16(vt + ((size_t)(bh * 8 + vs) * kT + ch * CC) * VB + ln,
                  &vs_[buf][0][0] + ln);
    }
  };

  stage(0, 0);
  for (int i = tid; i < VB * (kK + 4); i += 256) (&S0T[0][0])[i] = 0.f;

  for (int ch = 0; ch < NCH; ++ch) {
    const int cur = ch & 1;
    __syncthreads();                 // staging of `cur` drained; S0T coherent
    if (ch + 1 < NCH) stage(cur ^ 1, ch + 1);
    // ---- phase A: T1 = V - Khat S0 ; QS = Qhat S0 (thread = (tA,vA)) ----
    float accv = vs_[cur][tA][vA];
    float acco = 0.f;
#pragma unroll
    for (int k = 0; k < kK; k += 8) {
      float4 a0 = *(const float4*)&khs[cur][tA][k];
      float4 a1 = *(const float4*)&khs[cur][tA][k + 4];
      float4 q0 = *(const float4*)&qhs[cur][tA][k];
      float4 q1 = *(const float4*)&qhs[cur][tA][k + 4];
      float4 s0 = *(const float4*)&S0T[vA][k];
      float4 s1 = *(const float4*)&S0T[vA][k + 4];
      accv = fmaf(-a0.x, s0.x, accv); accv = fmaf(-a0.y, s0.y, accv);
      accv = fmaf(-a0.z, s0.z, accv); accv = fmaf(-a0.w, s0.w, accv);
      accv = fmaf(-a1.x, s1.x, accv); accv = fmaf(-a1.y, s1.y, accv);
      accv = fmaf(-a1.z, s1.z, accv); accv = fmaf(-a1.w, s1.w, accv);
      acco = fmaf(q0.x, s0.x, acco); acco = fmaf(q0.y, s0.y, acco);
      acco = fmaf(q0.z, s0.z, acco); acco = fmaf(q0.w, s0.w, acco);
      acco = fmaf(q1.x, s1.x, acco); acco = fmaf(q1.y, s1.y, acco);
      acco = fmaf(q1.z, s1.z, acco); acco = fmaf(q1.w, s1.w, acco);
    }
    T1s[tA][vA] = accv;
    QSs[tA][vA] = acco;
    __syncthreads();
    // ---- phase B: U = Winv @ T1 (Winv lower-tri incl. beta diag) ----
    {
      float u = 0.f;
#pragma unroll
      for (int s = 0; s < CC; ++s) u = fmaf(ws_[cur][tA][s], T1s[s][vA], u);
      Us[tA][vA] = u;
    }
    __syncthreads();
    // ---- phase C: O = QS + M U ; S0 = lam*S0 + Kbar^T U ----
    {
      float o = QSs[tA][vA];
#pragma unroll
      for (int s = 0; s < CC; ++s) o = fmaf(ms_[cur][tA][s], Us[s][vA], o);
      yf[((size_t)bh * kT + ch * CC + tA) * kV + cb + vA] = o;
    }
    {
      const int k0 = kg * 8;
      float4 p0 = *(const float4*)&lam_[cur][k0];
      float4 p1 = *(const float4*)&lam_[cur][k0 + 4];
      float4 a0 = *(const float4*)&S0T[vC][k0];
      float4 a1 = *(const float4*)&S0T[vC][k0 + 4];
      a0.x *= p0.x; a0.y *= p0.y; a0.z *= p0.z; a0.w *= p0.w;
      a1.x *= p1.x; a1.y *= p1.y; a1.z *= p1.z; a1.w *= p1.w;
#pragma unroll
      for (int s = 0; s < CC; ++s) {
        float uu = Us[s][vC];
        float4 b0 = *(const float4*)&kbs[cur][s][k0];
        float4 b1 = *(const float4*)&kbs[cur][s][k0 + 4];
        a0.x = fmaf(b0.x, uu, a0.x); a0.y = fmaf(b0.y, uu, a0.y);
        a0.z = fmaf(b0.z, uu, a0.z); a0.w = fmaf(b0.w, uu, a0.w);
        a1.x = fmaf(b1.x, uu, a1.x); a1.y = fmaf(b1.y, uu, a1.y);
        a1.z = fmaf(b1.z, uu, a1.z); a1.w = fmaf(b1.w, uu, a1.w);
      }
      *(float4*)&S0T[vC][k0]     = a0;
      *(float4*)&S0T[vC][k0 + 4] = a1;
    }
  }
}

// ---------------- rmsnorm * o_norm_w * sigmoid(gate+bg) -> bf16 -----------
__global__ __launch_bounds__(256) void postk(
    const float* __restrict__ yf, const u16* __restrict__ gateb,
    const float* __restrict__ bg, const float* __restrict__ onw,
    u16* __restrict__ ygb) {
  const int wid  = blockIdx.x * 4 + (threadIdx.x >> 6);
  const int lane = threadIdx.x & 63;
  const int h  = wid & 15;
  const int bt = wid >> 4;
  const int t  = bt & (kT - 1);
  const int b  = bt >> 11;
  const int v0 = lane * 2;
  const size_t yi = ((size_t)(b * kH + h) * kT + t) * kV + v0;
  float2 yv = *(const float2*)(yf + yi);
  float s = yv.x * yv.x + yv.y * yv.y;
#pragma unroll
  for (int m = 1; m < 64; m <<= 1) s += __shfl_xor(s, m);
  float scale = rsqrtf(s * (1.0f / 128.0f) + 1.1920929e-07f);
  const size_t gi = (size_t)bt * kHV + (size_t)h * kV + v0;
  u32 ug = *(const u32*)(gateb + gi);
  float g0 = bflo(ug) + bg[h * kV + v0];
  float g1 = bfhi(ug) + bg[h * kV + v0 + 1];
  float r0 = yv.x * scale * onw[v0] * sigmoidf(g0);
  float r1 = yv.y * scale * onw[v0 + 1] * sigmoidf(g1);
  *(u32*)(ygb + gi) = (u32)f2bf(r0) | ((u32)f2bf(r1) << 16);
}

// ---------------- host launcher ----------------
extern "C" void kernel_launch(void* const* d_in, const int* in_sizes, int n_in,
                              void* d_out, int out_size, void* d_ws, size_t ws_size,
                              hipStream_t stream) {
  (void)in_sizes; (void)n_in; (void)out_size; (void)ws_size;
  const float* x    = (const float*)d_in[0];
  const float* Wq   = (const float*)d_in[1];
  const float* Wk   = (const float*)d_in[2];
  const float* Wv   = (const float*)d_in[3];
  const float* Wf1  = (const float*)d_in[4];
  const float* Wf2  = (const float*)d_in[5];
  const float* Wb   = (const float*)d_in[6];
  const float* Wg1  = (const float*)d_in[7];
  const float* Wg2  = (const float*)d_in[8];
  const float* bg   = (const float*)d_in[9];
  const float* onw  = (const float*)d_in[10];
  const float* Wout = (const float*)d_in[11];
  const float* A_log   = (const float*)d_in[12];
  const float* dt_bias = (const float*)d_in[13];
  const float* qcw  = (const float*)d_in[14];
  const float* kcw  = (const float*)d_in[15];
  const float* vcw  = (const float*)d_in[16];

  char* ws = (char*)d_ws;
  u16* xb    = (u16*)(ws + OFF_XB);
  u16* Wqb   = (u16*)(ws + OFF_WQB);
  u16* Wkb   = (u16*)(ws + OFF_WKB);
  u16* Wvb   = (u16*)(ws + OFF_WVB);
  u16* Wf1b  = (u16*)(ws + OFF_WF1B);
  u16* Wg1b  = (u16*)(ws + OFF_WG1B);
  u16* Wf2b  = (u16*)(ws + OFF_WF2B);
  u16* Wg2b  = (u16*)(ws + OFF_WG2B);
  u16* Wbp   = (u16*)(ws + OFF_WBP);
  u16* Woutb = (u16*)(ws + OFF_WOUTB);
  u16* qraw  = (u16*)(ws + OFF_QRAW);
  u16* kraw  = (u16*)(ws + OFF_KRAW);
  u16* vraw  = (u16*)(ws + OFF_VRAW);
  u16* graw  = (u16*)(ws + OFF_GRAW);
  u16* gateb = (u16*)(ws + OFF_GATEB);
  u16* f1b   = (u16*)(ws + OFF_F1B);
  u16* g1b   = (u16*)(ws + OFF_G1B);
  u16* ygb   = (u16*)(ws + OFF_YGB);
  float* brawf = (float*)(ws + OFF_BRAW);
  float* qcf   = (float*)(ws + OFF_QC);
  float* kcf   = (float*)(ws + OFF_KC);
  float* vtf   = (float*)(ws + OFF_VC);
  float* gkf   = (float*)(ws + OFF_DEC);
  float* betaf = (float*)(ws + OFF_BETA);
  float* yff   = (float*)(ws + OFF_YF);
  float* lamf  = (float*)(ws + OFF_LAM);
  float* winvf = (float*)(ws + OFF_WINV);
  float* mmf   = (float*)(ws + OFF_MM);

  auto cast = [&](const float* src, u16* dst, int n) {
    cast_bf16<<<(n / 4 + 255) / 256, 256, 0, stream>>>(src, dst, n);
  };
  cast(x, xb, kM * kD);
  cast(Wq, Wqb, kHK * kD);
  cast(Wk, Wkb, kHK * kD);
  cast(Wv, Wvb, kHV * kD);
  cast(Wout, Woutb, kD * kHV);
  cast(Wf1, Wf1b, kV * kD);
  cast(Wg1, Wg1b, kV * kD);
  cast(Wf2, Wf2b, kHK * kV);
  cast(Wg2, Wg2b, kHV * kV);
  pad_wb<<<(128 * 2048 / 4 + 255) / 256, 256, 0, stream>>>(Wb, Wbp);

  dim3 blk(256);
  gemm_bt<true><<<dim3(kM / 128, kHK / 128), blk, 0, stream>>>(xb, Wqb, qraw, kM, kHK, kD);
  gemm_bt<true><<<dim3(kM / 128, kHK / 128), blk, 0, stream>>>(xb, Wkb, kraw, kM, kHK, kD);
  gemm_bt<true><<<dim3(kM / 128, kHV / 128), blk, 0, stream>>>(xb, Wvb, vraw, kM, kHV, kD);
  gemm_bt<true><<<dim3(kM / 128, 1), blk, 0, stream>>>(xb, Wf1b, f1b, kM, 128, kD);
  gemm_bt<true><<<dim3(kM / 128, 1), blk, 0, stream>>>(xb, Wg1b, g1b, kM, 128, kD);
  gemm_bt<false><<<dim3(kM / 128, 1), blk, 0, stream>>>(xb, Wbp, brawf, kM, 128, kD);
  gemm_bt<true><<<dim3(kM / 128, kHK / 128), blk, 0, stream>>>(f1b, Wf2b, graw, kM, kHK, kV);
  gemm_bt<true><<<dim3(kM / 128, kHV / 128), blk, 0, stream>>>(g1b, Wg2b, gateb, kM, kHV, kV);

  convprep<<<kB * kT * kH / 4, 256, 0, stream>>>(qraw, kraw, vraw, graw, brawf,
                                                 qcw, kcw, vcw, A_log, dt_bias,
                                                 qcf, kcf, vtf, gkf, betaf);

  kda_p1<<<32 * NCH, 256, 0, stream>>>(qcf, kcf, gkf, betaf, lamf, winvf, mmf);
  kda_p2<<<256, 256, 0, stream>>>(kcf, qcf, gkf, lamf, winvf, mmf, vtf, yff);

  postk<<<kB * kT * kH / 4, 256, 0, stream>>>(yff, gateb, bg, onw, ygb);

  gemm_bt<false><<<dim3(kM / 128, kD / 128), blk, 0, stream>>>(ygb, Woutb, (float*)d_out, kM, kD, kHV);
}

// Round 5
// 840.887 us; speedup vs baseline: 1.9271x; 1.3700x over previous
//
#include <hip/hip_runtime.h>

typedef unsigned short u16;
typedef unsigned int u32;

using short8 = __attribute__((ext_vector_type(8))) short;
using f32x4  = __attribute__((ext_vector_type(4))) float;

constexpr int kB = 2, kT = 2048, kD = 2048, kH = 16, kK = 128, kV = 128;
constexpr int kM  = kB * kT;   // 4096 tokens
constexpr int kHK = kH * kK;   // 2048
constexpr int kHV = kH * kV;   // 2048
constexpr int CC  = 16;        // scan chunk length
constexpr int NCH = kT / CC;   // 128 chunks

// ---------------- workspace layout (bytes). Overlays are deliberate. -------
// timeline: casts -> gemms(qkv,fgb,graw,gateb) -> convprep -> p1 -> p2 -> postk -> out-gemm
constexpr size_t OFF_XB    = 0;          // bf16 x [4096][2048] (dead after gemms)
constexpr size_t OFF_WQKV  = 16777216;   // bf16 [6144][2048] = Wq|Wk|Wv stacked (dead after qkv gemm)
constexpr size_t OFF_QC    = 0;          // f32 qc [32][2048][128] 33.5MB (convprep out; over XB+Wq+Wk)
constexpr size_t OFF_YF    = 0;          // f32 y [32][2048][128] (p2 out; qc dead after p1)
constexpr size_t OFF_WF1B  = 41943040;   // bf16 Wf1 [128][2048]
constexpr size_t OFF_WG1B  = 42467328;   // bf16 Wg1
constexpr size_t OFF_WBP   = 42991616;   // bf16 Wb padded [128][2048]  (F1|G1|BP contiguous = N=384)
constexpr size_t OFF_WF2B  = 43515904;   // bf16 Wf2
constexpr size_t OFF_WG2B  = 44040192;   // bf16 Wg2
constexpr size_t OFF_FGB   = 44564480;   // bf16 fgb [4096][384] (f1|g1|braw)
constexpr size_t OFF_QKVR  = 48758784;   // bf16 qkvraw [4096][6144] 50.3MB (dead after convprep)
constexpr size_t OFF_QHB   = 48758784;   // bf16 qhat [32][2048][128] (p1 out, over qkvraw)
constexpr size_t OFF_KBB   = 65536000;   // bf16 kbar
constexpr size_t OFF_KHB   = 82313216;   // bf16 khat
constexpr size_t OFF_YGB   = 82313216;   // bf16 y-gated (postk out, khb dead by then)
constexpr size_t OFF_GRAW  = 99090432;   // bf16 g_raw [4096][2048] (dead after convprep)
constexpr size_t OFF_LAM   = 99090432;   // f32 lam  [32][128][128] (p1 out, over graw)
constexpr size_t OFF_WINV  = 101187584;  // f32 winv [32][128][256]
constexpr size_t OFF_MM    = 105381888;  // f32 M    [32][128][256]
constexpr size_t OFF_GATEB = 115867648;  // bf16 gate [4096][2048]
constexpr size_t OFF_WOUTB = 132644864;  // bf16 Wout
constexpr size_t OFF_KC    = 141033472;  // f32 kc
constexpr size_t OFF_VT    = 174587904;  // f32 v transposed [bh*8+vs][t][16]
constexpr size_t OFF_GK    = 208142336;  // f32 log-decay g
constexpr size_t OFF_BETA  = 241696768;  // f32 beta [32][2048]
// total 241958912 bytes (~231 MB), unchanged from R4

// ---------------- small helpers ----------------
__device__ __forceinline__ u16 f2bf(float f) {
  union { float f; u32 u; } a; a.f = f;
  u32 u = a.u;
  u += 0x7fffu + ((u >> 16) & 1u);   // round-to-nearest-even
  return (u16)(u >> 16);
}
__device__ __forceinline__ float bflo(u32 u) {
  union { u32 u; float f; } a; a.u = u << 16; return a.f;
}
__device__ __forceinline__ float bfhi(u32 u) {
  union { u32 u; float f; } a; a.u = u & 0xffff0000u; return a.f;
}
__device__ __forceinline__ float sigmoidf(float x) { return 1.0f / (1.0f + expf(-x)); }

#define GL_AS1 __attribute__((address_space(1)))
#define GL_AS3 __attribute__((address_space(3)))
__device__ __forceinline__ void async_lds16(const void* g, void* l) {
  __builtin_amdgcn_global_load_lds((GL_AS1 u32*)(size_t)g,
                                   (GL_AS3 u32*)(u32)(size_t)l, 16, 0, 0);
}

// ---------------- fused cast of all f32->bf16 weights/x --------------------
__global__ __launch_bounds__(256) void cast_all(
    const float* __restrict__ x, const float* __restrict__ Wq,
    const float* __restrict__ Wk, const float* __restrict__ Wv,
    const float* __restrict__ Wout, const float* __restrict__ Wf1,
    const float* __restrict__ Wg1, const float* __restrict__ Wf2,
    const float* __restrict__ Wg2,
    u16* __restrict__ xb, u16* __restrict__ wqkv, u16* __restrict__ woutb,
    u16* __restrict__ wf1b, u16* __restrict__ wg1b, u16* __restrict__ wf2b,
    u16* __restrict__ wg2b) {
  long qi = (long)blockIdx.x * 256 + threadIdx.x;   // float4 index
  const float* src; u16* dst; long off;
  if (qi < 2097152)      { src = x;    dst = xb;             off = qi; }
  else if (qi < 3145728) { src = Wq;   dst = wqkv;           off = qi - 2097152; }
  else if (qi < 4194304) { src = Wk;   dst = wqkv + 4194304; off = qi - 3145728; }
  else if (qi < 5242880) { src = Wv;   dst = wqkv + 8388608; off = qi - 4194304; }
  else if (qi < 6291456) { src = Wout; dst = woutb;          off = qi - 5242880; }
  else if (qi < 6356992) { src = Wf1;  dst = wf1b;           off = qi - 6291456; }
  else if (qi < 6422528) { src = Wg1;  dst = wg1b;           off = qi - 6356992; }
  else if (qi < 6488064) { src = Wf2;  dst = wf2b;           off = qi - 6422528; }
  else                   { src = Wg2;  dst = wg2b;           off = qi - 6488064; }
  long i = off * 4;
  float4 v = *(const float4*)(src + i);
  uint2 st;
  st.x = (u32)f2bf(v.x) | ((u32)f2bf(v.y) << 16);
  st.y = (u32)f2bf(v.z) | ((u32)f2bf(v.w) << 16);
  *(uint2*)(dst + i) = st;
}

// Wb [16,2048] f32 -> [128,2048] bf16 zero-padded
__global__ __launch_bounds__(256) void pad_wb(const float* __restrict__ Wb,
                                              u16* __restrict__ out) {
  int i = (blockIdx.x * 256 + threadIdx.x) * 4;  // < 262144
  int row = i >> 11;
  uint2 st; st.x = 0; st.y = 0;
  if (row < 16) {
    float4 v = *(const float4*)(Wb + i);
    st.x = (u32)f2bf(v.x) | ((u32)f2bf(v.y) << 16);
    st.y = (u32)f2bf(v.z) | ((u32)f2bf(v.w) << 16);
  }
  *(uint2*)(out + i) = st;
}

// ---------------- bf16 MFMA GEMM:  C[m,n] = sum_k A[m,k] * B[n,k] ----------
// A row stride lda, B row stride ldb, C row stride ldc (elements). K%32==0.
template <bool BF16OUT>
__global__ __launch_bounds__(256) void gemm_bt(const u16* __restrict__ A,
                                               const u16* __restrict__ B,
                                               void* __restrict__ Cout,
                                               int lda, int ldb, int ldc, int K) {
  __shared__ u16 As[128 * 32];
  __shared__ u16 Bs[128 * 32];
  const int tid  = threadIdx.x;
  const int lane = tid & 63;
  const int wave = tid >> 6;
  const int wm = (wave >> 1) * 64;
  const int wn = (wave & 1) * 64;
  const long row0 = (long)blockIdx.x * 128;
  const long col0 = (long)blockIdx.y * 128;
  const int srow = tid >> 2;
  const int scol = (tid & 3) * 8;
  const u16* aptr = A + (row0 + srow) * (size_t)lda + scol;
  const u16* bptr = B + (col0 + srow) * (size_t)ldb + scol;
  u16* asd  = &As[tid * 8];
  u16* asd2 = &As[2048 + tid * 8];
  u16* bsd  = &Bs[tid * 8];
  u16* bsd2 = &Bs[2048 + tid * 8];
  const int mrow = lane & 15;
  const int kq = (lane >> 4) * 8;
  f32x4 acc[4][4] = {};
  for (int k0 = 0; k0 < K; k0 += 32) {
    async_lds16(aptr, asd);
    async_lds16(aptr + (size_t)64 * lda, asd2);
    async_lds16(bptr, bsd);
    async_lds16(bptr + (size_t)64 * ldb, bsd2);
    aptr += 32; bptr += 32;
    __syncthreads();
    short8 af[4], bfr[4];
#pragma unroll
    for (int i = 0; i < 4; ++i)
      af[i] = *(const short8*)(&As[(wm + i * 16 + mrow) * 32 + kq]);
#pragma unroll
    for (int j = 0; j < 4; ++j)
      bfr[j] = *(const short8*)(&Bs[(wn + j * 16 + mrow) * 32 + kq]);
#pragma unroll
    for (int i = 0; i < 4; ++i)
#pragma unroll
      for (int j = 0; j < 4; ++j)
        acc[i][j] = __builtin_amdgcn_mfma_f32_16x16x32_bf16(af[i], bfr[j], acc[i][j], 0, 0, 0);
    __syncthreads();
  }
  const int cn = lane & 15;
  const int rq = (lane >> 4) * 4;
#pragma unroll
  for (int i = 0; i < 4; ++i)
#pragma unroll
    for (int j = 0; j < 4; ++j) {
      size_t r = (size_t)(row0 + wm + i * 16 + rq);
      size_t c = (size_t)(col0 + wn + j * 16 + cn);
#pragma unroll
      for (int rr = 0; rr < 4; ++rr) {
        if constexpr (BF16OUT)
          ((u16*)Cout)[(r + rr) * ldc + c] = f2bf(acc[i][j][rr]);
        else
          ((float*)Cout)[(r + rr) * ldc + c] = acc[i][j][rr];
      }
    }
}

// ---------------- conv(4-tap causal) + silu + l2norm + g + beta ------------
__global__ __launch_bounds__(256) void convprep(
    const u16* __restrict__ qkv, const u16* __restrict__ graw,
    const u16* __restrict__ fgb,
    const float* __restrict__ qcw, const float* __restrict__ kcw,
    const float* __restrict__ vcw, const float* __restrict__ A_log,
    const float* __restrict__ dt_bias,
    float* __restrict__ qc, float* __restrict__ kc, float* __restrict__ vt,
    float* __restrict__ gdec, float* __restrict__ beta) {
  const int wid  = blockIdx.x * 4 + (threadIdx.x >> 6);
  const int lane = threadIdx.x & 63;
  const int h  = wid & 15;
  const int bt = wid >> 4;        // b*T + t
  const int t  = bt & (kT - 1);
  const int b  = bt >> 11;
  const int c0 = lane * 2;
  const size_t colofs = (size_t)h * kK + c0;
  const size_t rowb = (size_t)bt * 6144 + colofs;
  const float* wq = qcw + colofs * 4;
  const float* wk = kcw + colofs * 4;
  const float* wv = vcw + colofs * 4;
  float qa0 = 0, qa1 = 0, ka0 = 0, ka1 = 0, va0 = 0, va1 = 0;
#pragma unroll
  for (int i = 0; i < 4; ++i) {
    int tt = t - 3 + i;
    if (tt >= 0) {
      size_t ro = rowb - (size_t)(3 - i) * 6144;
      u32 uq = *(const u32*)(qkv + ro);
      u32 uk = *(const u32*)(qkv + ro + 2048);
      u32 uv = *(const u32*)(qkv + ro + 4096);
      qa0 += bflo(uq) * wq[i];  qa1 += bfhi(uq) * wq[4 + i];
      ka0 += bflo(uk) * wk[i];  ka1 += bfhi(uk) * wk[4 + i];
      va0 += bflo(uv) * wv[i];  va1 += bfhi(uv) * wv[4 + i];
    }
  }
  qa0 *= sigmoidf(qa0); qa1 *= sigmoidf(qa1);
  ka0 *= sigmoidf(ka0); ka1 *= sigmoidf(ka1);
  va0 *= sigmoidf(va0); va1 *= sigmoidf(va1);
  float sq = qa0 * qa0 + qa1 * qa1;
  float sk = ka0 * ka0 + ka1 * ka1;
#pragma unroll
  for (int m = 1; m < 64; m <<= 1) {
    sq += __shfl_xor(sq, m);
    sk += __shfl_xor(sk, m);
  }
  float qinv = 1.0f / fmaxf(sqrtf(sq), 1e-12f);
  float kinv = 1.0f / fmaxf(sqrtf(sk), 1e-12f);
  const int bh = b * kH + h;
  const size_t outb = ((size_t)bh * kT + t) * kK + c0;
  *(float2*)(qc + outb) = make_float2(qa0 * qinv, qa1 * qinv);
  *(float2*)(kc + outb) = make_float2(ka0 * kinv, ka1 * kinv);
  const size_t vtb = ((size_t)(bh * 8 + (c0 >> 4)) * kT + t) * 16 + (c0 & 15);
  *(float2*)(vt + vtb) = make_float2(va0, va1);
  u32 ug = *(const u32*)(graw + (size_t)bt * kHK + colofs);
  float Ae = expf(A_log[h]);
  float g0 = bflo(ug) + dt_bias[colofs];
  float g1 = bfhi(ug) + dt_bias[colofs + 1];
  float sp0 = (g0 > 15.f) ? g0 : log1pf(expf(g0));
  float sp1 = (g1 > 15.f) ? g1 : log1pf(expf(g1));
  *(float2*)(gdec + outb) = make_float2(-Ae * sp0, -Ae * sp1);
  if (lane == 0) {
    float bv = bflo((u32)fgb[(size_t)bt * 384 + 256 + h]);
    beta[(size_t)bh * kT + t] = sigmoidf(bv);
  }
}

// ---------------- KDA pass 1: per (bh,chunk) transforms --------------------
// Emits bf16 khat=k*e^G, qhat=q*e^G, kbar=k*e^{GC-G}; f32 lam=e^{GC},
// Winv=(I+B trilA)^{-1}B and M -- built from the ROUNDED khat/qhat/kbar so
// the chunk algebra is exactly consistent with p2's bf16 MFMA operands.
__global__ __launch_bounds__(256) void kda_p1(
    const float* __restrict__ qc, const float* __restrict__ kc,
    const float* __restrict__ gk, const float* __restrict__ betap,
    u16* __restrict__ qhb, u16* __restrict__ khb, u16* __restrict__ kbb,
    float* __restrict__ lamC, float* __restrict__ winv,
    float* __restrict__ mmat) {
  __shared__ float kL[CC][132], qL[CC][132], gL[CC][132];
  __shared__ float As[CC][CC], Ms[CC][CC];
  __shared__ float bet[CC];
  const int tid = threadIdx.x;
  const int bh = blockIdx.x >> 7;
  const int ch = blockIdx.x & 127;
  const size_t base = ((size_t)bh * kT + ch * CC) * kK;
  const int e = tid * 8;
  const int t = e >> 7, k = e & 127;
  {
    *(float4*)&kL[t][k]     = *(const float4*)(kc + base + e);
    *(float4*)&kL[t][k + 4] = *(const float4*)(kc + base + e + 4);
    *(float4*)&qL[t][k]     = *(const float4*)(qc + base + e);
    *(float4*)&qL[t][k + 4] = *(const float4*)(qc + base + e + 4);
    *(float4*)&gL[t][k]     = *(const float4*)(gk + base + e);
    *(float4*)&gL[t][k + 4] = *(const float4*)(gk + base + e + 4);
    if (tid < CC) bet[tid] = betap[(size_t)bh * kT + ch * CC + tid];
  }
  __syncthreads();
  if (tid < kK) {        // inclusive cumsum of g over t -> G
    float a = gL[0][tid];
#pragma unroll
    for (int tt = 1; tt < CC; ++tt) { a += gL[tt][tid]; gL[tt][tid] = a; }
  }
  __syncthreads();
  float khr[8], qhr[8], kbw[8];
  u32 pk[4] = {0,0,0,0}, pq[4] = {0,0,0,0}, pb[4] = {0,0,0,0};
#pragma unroll
  for (int j = 0; j < 8; ++j) {
    float G  = gL[t][k + j];
    float GC = gL[CC - 1][k + j];
    float eg = __expf(G);
    float kh = kL[t][k + j] * eg;
    float qh = qL[t][k + j] * eg;
    float kb = kL[t][k + j] * __expf(GC - G);
    u16 a = f2bf(kh), b_ = f2bf(qh), c = f2bf(kb);
    pk[j >> 1] |= ((u32)a)  << (16 * (j & 1));
    pq[j >> 1] |= ((u32)b_) << (16 * (j & 1));
    pb[j >> 1] |= ((u32)c)  << (16 * (j & 1));
    khr[j] = bflo(a);
    qhr[j] = bflo(b_);
    kbw[j] = bflo(c) * __expf(-GC);   // kbar * e^{-GC}
  }
  *(uint4*)(khb + base + e) = *(uint4*)pk;
  *(uint4*)(qhb + base + e) = *(uint4*)pq;
  *(uint4*)(kbb + base + e) = *(uint4*)pb;
  if (tid < kK)
    lamC[((size_t)bh * NCH + ch) * kK + tid] = __expf(gL[CC - 1][tid]);
  __syncthreads();   // all GC reads done before overwrite
#pragma unroll
  for (int j = 0; j < 8; ++j) {
    kL[t][k + j] = khr[j];
    qL[t][k + j] = qhr[j];
    gL[t][k + j] = kbw[j];
  }
  __syncthreads();
  {  // A[t][s]=khat_t . (kbar_s e^{-GC}); M[t][s]=qhat_t . (kbar_s e^{-GC})
    const int t2 = tid >> 4, s = tid & 15;
    float av = 0.f, mv = 0.f;
    for (int kk = 0; kk < kK; ++kk) {
      float w = gL[s][kk];
      av = fmaf(kL[t2][kk], w, av);
      mv = fmaf(qL[t2][kk], w, mv);
    }
    As[t2][s] = (s < t2)  ? av : 0.f;
    Ms[t2][s] = (s <= t2) ? mv : 0.f;
  }
  __syncthreads();
  if (tid < CC) {  // X = (I + B trilA)^{-1} B, column s
    const int s = tid;
    float x[CC];
#pragma unroll
    for (int tt = 0; tt < CC; ++tt) {
      float sum = 0.f;
      for (int r = 0; r < tt; ++r) sum += As[tt][r] * x[r];
      x[tt] = ((tt == s) ? bet[tt] : 0.f) - bet[tt] * sum;
    }
    const size_t wb = ((size_t)bh * NCH + ch) * 256;
#pragma unroll
    for (int tt = 0; tt < CC; ++tt) winv[wb + tt * 16 + s] = x[tt];
  }
  mmat[((size_t)bh * NCH + ch) * 256 + tid] = Ms[tid >> 4][tid & 15];
}

// ---------------- KDA pass 2: MFMA chunk recurrence ------------------------
// 256 blocks = 32 bh x 8 v-splits(16 cols), 4 waves. Wave w owns state rows
// k in [w*32,w*32+32) as 2 MFMA accumulators (f32). State & U round-trip
// through LDS as bf16 hi/lo pairs (~fp24). Per chunk:
//   T1 = V - Khat S0 ; U = Winv T1 ; O = Qhat S0 + M U ; S = lam*S0 + Kbar^T U
__global__ __launch_bounds__(256) void kda_p2(
    const u16* __restrict__ khb, const u16* __restrict__ qhb,
    const u16* __restrict__ kbb, const float* __restrict__ lamC,
    const float* __restrict__ winv, const float* __restrict__ mmat,
    const float* __restrict__ vt, float* __restrict__ yf) {
  __shared__ u16 khs[2][CC][136];
  __shared__ u16 qhs[2][CC][136];
  __shared__ u16 kbs[2][kK][40];   // [k][s], cols 16..31 stay zero
  __shared__ float vsx[2][CC][17];
  __shared__ float wsx[2][CC][16];
  __shared__ float msx[2][CC][16];
  __shared__ float lamx[2][kK];
  __shared__ u16 s0h[CC][136];     // S^T bf16-hi [v][k]
  __shared__ u16 s0l[CC][136];     // S^T bf16-lo
  __shared__ float pd[4][CC][17];
  __shared__ float qd[4][CC][17];
  __shared__ float t1r[CC][17];
  __shared__ float ufx[CC][17];
  __shared__ u16 ush[CC][40];      // U^T bf16-hi [v][s], cols 16..31 zero
  __shared__ u16 usl[CC][40];
  const int tid = threadIdx.x;
  const int w = tid >> 6, lane = tid & 63;
  const int m15 = lane & 15, q = lane >> 4, q8 = q * 8;
  const int t_ = tid >> 4, v_ = tid & 15;
  const int blk = blockIdx.x;
  const int bh = (blk & 7) + ((blk >> 6) << 3);  // same-bh blocks share XCD slot
  const int vs = (blk >> 3) & 7;
  const int cb = vs * 16;
  // zero init (state, transposed-with-zero-tail arrays)
  for (int i = tid; i < CC * 136 / 2; i += 256) { ((u32*)s0h)[i] = 0; ((u32*)s0l)[i] = 0; }
  for (int i = tid; i < 2 * kK * 40 / 2; i += 256) ((u32*)kbs)[i] = 0;
  for (int i = tid; i < CC * 40 / 2; i += 256) { ((u32*)ush)[i] = 0; ((u32*)usl)[i] = 0; }

  uint4 rkh, rqh, rkb; float rv, rw, rm, rl;
  auto loadCh = [&](int ch) {
    const size_t cbase = ((size_t)bh * kT + ch * CC) * kK;
    rkh = *(const uint4*)(khb + cbase + tid * 8);
    rqh = *(const uint4*)(qhb + cbase + tid * 8);
    rkb = *(const uint4*)(kbb + cbase + tid * 8);
    rv  = vt[((size_t)(bh * 8 + vs) * kT + ch * CC) * 16 + tid];
    const size_t sm = (size_t)bh * NCH + ch;
    rw  = winv[sm * 256 + tid];
    rm  = mmat[sm * 256 + tid];
    rl  = (tid < kK) ? lamC[sm * kK + tid] : 0.f;
  };
  auto writeStage = [&](int b) {
    const int tr = tid >> 4, tc = (tid & 15) * 8;
    *(uint4*)&khs[b][tr][tc] = rkh;
    *(uint4*)&qhs[b][tr][tc] = rqh;
    u16 kv[8]; *(uint4*)kv = rkb;
#pragma unroll
    for (int j = 0; j < 8; ++j) kbs[b][tc + j][tr] = kv[j];   // transpose [k][s]
    vsx[b][tr][tid & 15] = rv;
    wsx[b][tr][tid & 15] = rw;
    msx[b][tr][tid & 15] = rm;
    if (tid < kK) lamx[b][tid] = rl;
  };

  f32x4 St[2] = {};
  loadCh(0);
  for (int ch = 0; ch < NCH; ++ch) {
    const int b = ch & 1;
    writeStage(b);
    if (ch + 1 < NCH) loadCh(ch + 1);
    __syncthreads();  // B1: stage + S0 hi/lo visible
    // phase A: wave-partial K-slice products
    short8 aK = *(const short8*)&khs[b][m15][w * 32 + q8];
    short8 aQ = *(const short8*)&qhs[b][m15][w * 32 + q8];
    short8 sH = *(const short8*)&s0h[m15][w * 32 + q8];
    short8 sL = *(const short8*)&s0l[m15][w * 32 + q8];
    f32x4 z = {0.f, 0.f, 0.f, 0.f};
    f32x4 P  = __builtin_amdgcn_mfma_f32_16x16x32_bf16(aK, sL, z, 0, 0, 0);
    P        = __builtin_amdgcn_mfma_f32_16x16x32_bf16(aK, sH, P, 0, 0, 0);
    f32x4 Qp = __builtin_amdgcn_mfma_f32_16x16x32_bf16(aQ, sL, z, 0, 0, 0);
    Qp       = __builtin_amdgcn_mfma_f32_16x16x32_bf16(aQ, sH, Qp, 0, 0, 0);
#pragma unroll
    for (int r = 0; r < 4; ++r) {
      pd[w][q * 4 + r][m15] = P[r];
      qd[w][q * 4 + r][m15] = Qp[r];
    }
    __syncthreads();  // B2
    float t1 = vsx[b][t_][v_] -
               ((pd[0][t_][v_] + pd[1][t_][v_]) + (pd[2][t_][v_] + pd[3][t_][v_]));
    float qs = (qd[0][t_][v_] + qd[1][t_][v_]) + (qd[2][t_][v_] + qd[3][t_][v_]);
    t1r[t_][v_] = t1;
    __syncthreads();  // B3
    float u = 0.f;
#pragma unroll
    for (int s = 0; s < CC; ++s) u = fmaf(wsx[b][t_][s], t1r[s][v_], u);
    ufx[t_][v_] = u;
    u16 uh = f2bf(u);
    ush[v_][t_] = uh;
    usl[v_][t_] = f2bf(u - bflo(uh));
    __syncthreads();  // B4
    float o = qs;
#pragma unroll
    for (int s = 0; s < CC; ++s) o = fmaf(msx[b][t_][s], ufx[s][v_], o);
    yf[((size_t)bh * kT + ch * CC + t_) * kV + cb + v_] = o;
    // state update: S = lam*S + Kbar^T U  (hi/lo mfma pair per tile)
    short8 bH = *(const short8*)&ush[m15][q8];
    short8 bL = *(const short8*)&usl[m15][q8];
#pragma unroll
    for (int j = 0; j < 2; ++j) {
      const int kt = w * 32 + j * 16;
      f32x4 S = St[j];
#pragma unroll
      for (int r = 0; r < 4; ++r) S[r] *= lamx[b][kt + q * 4 + r];
      short8 aB = *(const short8*)&kbs[b][kt + m15][q8];
      S = __builtin_amdgcn_mfma_f32_16x16x32_bf16(aB, bL, S, 0, 0, 0);
      S = __builtin_amdgcn_mfma_f32_16x16x32_bf16(aB, bH, S, 0, 0, 0);
      St[j] = S;
      u16 h0 = f2bf(S[0]), h1 = f2bf(S[1]), h2 = f2bf(S[2]), h3 = f2bf(S[3]);
      uint2 hw; hw.x = (u32)h0 | ((u32)h1 << 16); hw.y = (u32)h2 | ((u32)h3 << 16);
      *(uint2*)&s0h[m15][kt + q * 4] = hw;
      uint2 lw;
      lw.x = (u32)f2bf(S[0] - bflo(h0)) | ((u32)f2bf(S[1] - bflo(h1)) << 16);
      lw.y = (u32)f2bf(S[2] - bflo(h2)) | ((u32)f2bf(S[3] - bflo(h3)) << 16);
      *(uint2*)&s0l[m15][kt + q * 4] = lw;
    }
  }
}

// ---------------- rmsnorm * o_norm_w * sigmoid(gate+bg) -> bf16 -----------
__global__ __launch_bounds__(256) void postk(
    const float* __restrict__ yf, const u16* __restrict__ gateb,
    const float* __restrict__ bg, const float* __restrict__ onw,
    u16* __restrict__ ygb) {
  const int wid  = blockIdx.x * 4 + (threadIdx.x >> 6);
  const int lane = threadIdx.x & 63;
  const int h  = wid & 15;
  const int bt = wid >> 4;
  const int t  = bt & (kT - 1);
  const int b  = bt >> 11;
  const int v0 = lane * 2;
  const size_t yi = ((size_t)(b * kH + h) * kT + t) * kV + v0;
  float2 yv = *(const float2*)(yf + yi);
  float s = yv.x * yv.x + yv.y * yv.y;
#pragma unroll
  for (int m = 1; m < 64; m <<= 1) s += __shfl_xor(s, m);
  float scale = rsqrtf(s * (1.0f / 128.0f) + 1.1920929e-07f);
  const size_t gi = (size_t)bt * kHV + (size_t)h * kV + v0;
  u32 ug = *(const u32*)(gateb + gi);
  float g0 = bflo(ug) + bg[h * kV + v0];
  float g1 = bfhi(ug) + bg[h * kV + v0 + 1];
  float r0 = yv.x * scale * onw[v0] * sigmoidf(g0);
  float r1 = yv.y * scale * onw[v0 + 1] * sigmoidf(g1);
  *(u32*)(ygb + gi) = (u32)f2bf(r0) | ((u32)f2bf(r1) << 16);
}

// ---------------- host launcher ----------------
extern "C" void kernel_launch(void* const* d_in, const int* in_sizes, int n_in,
                              void* d_out, int out_size, void* d_ws, size_t ws_size,
                              hipStream_t stream) {
  (void)in_sizes; (void)n_in; (void)out_size; (void)ws_size;
  const float* x    = (const float*)d_in[0];
  const float* Wq   = (const float*)d_in[1];
  const float* Wk   = (const float*)d_in[2];
  const float* Wv   = (const float*)d_in[3];
  const float* Wf1  = (const float*)d_in[4];
  const float* Wf2  = (const float*)d_in[5];
  const float* Wb   = (const float*)d_in[6];
  const float* Wg1  = (const float*)d_in[7];
  const float* Wg2  = (const float*)d_in[8];
  const float* bg   = (const float*)d_in[9];
  const float* onw  = (const float*)d_in[10];
  const float* Wout = (const float*)d_in[11];
  const float* A_log   = (const float*)d_in[12];
  const float* dt_bias = (const float*)d_in[13];
  const float* qcw  = (const float*)d_in[14];
  const float* kcw  = (const float*)d_in[15];
  const float* vcw  = (const float*)d_in[16];

  char* ws = (char*)d_ws;
  u16* xb     = (u16*)(ws + OFF_XB);
  u16* wqkv   = (u16*)(ws + OFF_WQKV);
  u16* wf1b   = (u16*)(ws + OFF_WF1B);
  u16* wg1b   = (u16*)(ws + OFF_WG1B);
  u16* wbp    = (u16*)(ws + OFF_WBP);
  u16* wf2b   = (u16*)(ws + OFF_WF2B);
  u16* wg2b   = (u16*)(ws + OFF_WG2B);
  u16* woutb  = (u16*)(ws + OFF_WOUTB);
  u16* fgb    = (u16*)(ws + OFF_FGB);
  u16* qkvraw = (u16*)(ws + OFF_QKVR);
  u16* graw   = (u16*)(ws + OFF_GRAW);
  u16* gateb  = (u16*)(ws + OFF_GATEB);
  u16* qhb    = (u16*)(ws + OFF_QHB);
  u16* khb    = (u16*)(ws + OFF_KHB);
  u16* kbb    = (u16*)(ws + OFF_KBB);
  u16* ygb    = (u16*)(ws + OFF_YGB);
  float* qcf   = (float*)(ws + OFF_QC);
  float* kcf   = (float*)(ws + OFF_KC);
  float* vtf   = (float*)(ws + OFF_VT);
  float* gkf   = (float*)(ws + OFF_GK);
  float* betaf = (float*)(ws + OFF_BETA);
  float* yff   = (float*)(ws + OFF_YF);
  float* lamf  = (float*)(ws + OFF_LAM);
  float* winvf = (float*)(ws + OFF_WINV);
  float* mmf   = (float*)(ws + OFF_MM);

  cast_all<<<25600, 256, 0, stream>>>(x, Wq, Wk, Wv, Wout, Wf1, Wg1, Wf2, Wg2,
                                      xb, wqkv, woutb, wf1b, wg1b, wf2b, wg2b);
  pad_wb<<<(128 * 2048 / 4 + 255) / 256, 256, 0, stream>>>(Wb, wbp);

  dim3 blk(256);
  // qkv: [4096,6144] = x @ [Wq;Wk;Wv]^T
  gemm_bt<true><<<dim3(kM / 128, 6144 / 128), blk, 0, stream>>>(
      xb, wqkv, qkvraw, kD, kD, 6144, kD);
  // fgb: [4096,384] = x @ [Wf1;Wg1;Wbp]^T
  gemm_bt<true><<<dim3(kM / 128, 384 / 128), blk, 0, stream>>>(
      xb, wf1b, fgb, kD, kD, 384, kD);
  // graw: [4096,2048] = f1 @ Wf2^T   (A = fgb cols 0..127, lda 384)
  gemm_bt<true><<<dim3(kM / 128, kHK / 128), blk, 0, stream>>>(
      fgb, wf2b, graw, 384, kV, kHK, kV);
  // gateb: [4096,2048] = g1 @ Wg2^T  (A = fgb cols 128..255)
  gemm_bt<true><<<dim3(kM / 128, kHV / 128), blk, 0, stream>>>(
      fgb + 128, wg2b, gateb, 384, kV, kHV, kV);

  convprep<<<kB * kT * kH / 4, 256, 0, stream>>>(qkvraw, graw, fgb,
                                                 qcw, kcw, vcw, A_log, dt_bias,
                                                 qcf, kcf, vtf, gkf, betaf);

  kda_p1<<<32 * NCH, 256, 0, stream>>>(qcf, kcf, gkf, betaf,
                                       qhb, khb, kbb, lamf, winvf, mmf);
  kda_p2<<<256, 256, 0, stream>>>(khb, qhb, kbb, lamf, winvf, mmf, vtf, yff);

  postk<<<kB * kT * kH / 4, 256, 0, stream>>>(yff, gateb, bg, onw, ygb);

  // out: [4096,2048] = yg @ Wout^T
  gemm_bt<false><<<dim3(kM / 128, kD / 128), blk, 0, stream>>>(
      ygb, woutb, (float*)d_out, kHV, kHV, kD, kHV);
}